// Round 3
// baseline (448.462 us; speedup 1.0000x reference)
//
#include <hip/hip_runtime.h>
#include <hip/hip_bf16.h>
#include <stdint.h>

// ArcFace fused: out[n][c] = 64 * margin(clip( (x_hat . w_c) / ||w_c|| ))
// N=512, D=512, C=100000.
// R3 structure: one block per 64-class panel (grid 1563), BM = all 512 rows.
//   Phase 1: stage whole 64x512 f32 W panel -> bf16 LDS (pipelined, 16 loads/thread),
//            accumulate per-class sum-of-squares. ONE barrier.
//   Phase 2: barrier-free K-loop: A frags direct from global (L2-hot 0.5 MB),
//            B frags from LDS, 16 MFMA/wave/step.
//   Epilogue: rsqrt(ss) * clip * 64.
// W is fetched from HBM exactly once (no inter-block panel sharing).

#define NROWS 512
#define DDIM 512
#define NCLS 100000
#define BN 64
#define BSTR 520   // Bs row stride in bf16 elems (512 + 8 pad -> even bank spread)

typedef __attribute__((ext_vector_type(8))) short bf16x8;
typedef __attribute__((ext_vector_type(8))) unsigned short u16x8;
typedef __attribute__((ext_vector_type(4))) float f32x4;

__device__ __forceinline__ unsigned short f2bf(float x) {
    union { float f; uint32_t u; } c; c.f = x;
    uint32_t r = (c.u + 0x7FFFu + ((c.u >> 16) & 1u)) >> 16;
    return (unsigned short)r;
}

// One wave per row: normalize x rows to unit L2 norm, store bf16.
__global__ __launch_bounds__(256)
void rownorm_x(const float* __restrict__ in, unsigned short* __restrict__ out) {
    const int row  = blockIdx.x * 4 + (threadIdx.x >> 6);
    const int lane = threadIdx.x & 63;

    const float4* p = (const float4*)(in + (size_t)row * DDIM);
    float4 v0 = p[lane];
    float4 v1 = p[64 + lane];

    float ss = v0.x*v0.x + v0.y*v0.y + v0.z*v0.z + v0.w*v0.w
             + v1.x*v1.x + v1.y*v1.y + v1.z*v1.z + v1.w*v1.w;
    #pragma unroll
    for (int off = 32; off > 0; off >>= 1) ss += __shfl_xor(ss, off);
    const float r = rsqrtf(ss);

    unsigned short* orow = out + (size_t)row * DDIM;
    ushort4 o0, o1;
    o0.x = f2bf(v0.x * r); o0.y = f2bf(v0.y * r);
    o0.z = f2bf(v0.z * r); o0.w = f2bf(v0.w * r);
    o1.x = f2bf(v1.x * r); o1.y = f2bf(v1.y * r);
    o1.z = f2bf(v1.z * r); o1.w = f2bf(v1.w * r);
    *(ushort4*)(orow + lane * 4) = o0;
    *(ushort4*)(orow + 256 + lane * 4) = o1;
}

// 512 threads = 8 waves. Wave w owns output rows [w*64, w*64+64) x all 64 cols.
// Per wave per K-step: 4x4 frags of 16x16x32 = 16 MFMA. acc = 64 VGPR.
__global__ __launch_bounds__(512, 4)
void arcface_gemm_fused(const unsigned short* __restrict__ A,
                        const float* __restrict__ W,
                        float* __restrict__ out) {
    __shared__ unsigned short Bs[BN * BSTR];   // 66560 B
    __shared__ float ssp[BN * 8];              // 2 KB per-class ss partials

    const int t    = threadIdx.x;
    const int lane = t & 63;
    const int wid  = t >> 6;
    const int fr   = lane & 15;
    const int kg   = (lane >> 4) << 3;     // k-offset in bf16 elems: 0,8,16,24
    const int colBase = blockIdx.x * BN;

    // ---- Phase 1: stage whole B panel (64 x 512 f32), cvt->bf16 LDS, ss ----
    // thread -> panel row (wid*8 + lane/8), 8 threads per row, 64 f32 each
    const int prow  = (wid << 3) + (lane >> 3);
    const int pcolB = (lane & 7) << 4;         // f32 col base within row
    const int cls   = colBase + prow;
    const bool v    = cls < NCLS;
    const float* gW = W + (size_t)cls * DDIM + pcolB;

    float4 pf[16];
    if (v) {
        #pragma unroll
        for (int c = 0; c < 4; ++c)            // 4 col-chunks of 128 f32
            #pragma unroll
            for (int j = 0; j < 4; ++j)        // 4 float4 per chunk
                pf[c * 4 + j] = *(const float4*)(gW + c * 128 + j * 4);
    } else {
        #pragma unroll
        for (int i = 0; i < 16; ++i) pf[i] = float4{0.f, 0.f, 0.f, 0.f};
    }

    float ss = 0.f;
    #pragma unroll
    for (int i = 0; i < 16; ++i)
        ss += pf[i].x*pf[i].x + pf[i].y*pf[i].y + pf[i].z*pf[i].z + pf[i].w*pf[i].w;

    #pragma unroll
    for (int c = 0; c < 4; ++c) {
        #pragma unroll
        for (int h = 0; h < 2; ++h) {          // two b128 writes per chunk
            const float4 p0 = pf[c * 4 + h * 2];
            const float4 p1 = pf[c * 4 + h * 2 + 1];
            u16x8 o;
            o[0] = f2bf(p0.x); o[1] = f2bf(p0.y); o[2] = f2bf(p0.z); o[3] = f2bf(p0.w);
            o[4] = f2bf(p1.x); o[5] = f2bf(p1.y); o[6] = f2bf(p1.z); o[7] = f2bf(p1.w);
            *(u16x8*)&Bs[prow * BSTR + pcolB + c * 128 + h * 8] = o;
        }
    }
    ssp[prow * 8 + (lane & 7)] = ss;
    __syncthreads();   // the ONLY barrier

    // ---- Phase 2: barrier-free K-loop ----
    f32x4 acc[4][4] = {};
    const unsigned short* Ab = A + (size_t)(wid * 64 + fr) * DDIM + kg;

    #pragma unroll 4
    for (int kt = 0; kt < DDIM; kt += 32) {
        bf16x8 a[4], b[4];
        #pragma unroll
        for (int m = 0; m < 4; ++m)   // direct global (L2-hot), 16B per lane
            a[m] = *(const bf16x8*)(Ab + (size_t)m * 16 * DDIM + kt);
        #pragma unroll
        for (int n = 0; n < 4; ++n)
            b[n] = *(const bf16x8*)&Bs[(n * 16 + fr) * BSTR + kt + kg];
        #pragma unroll
        for (int m = 0; m < 4; ++m)
            #pragma unroll
            for (int n = 0; n < 4; ++n)
                acc[m][n] = __builtin_amdgcn_mfma_f32_16x16x32_bf16(
                    a[m], b[n], acc[m][n], 0, 0, 0);
    }

    // ---- Epilogue: per-class rsqrt, clip, scale, store ----
    const float lo = -1.0f + 1e-7f, hi = 1.0f - 1e-7f;
    float rn[4];
    #pragma unroll
    for (int n = 0; n < 4; ++n) {
        const int cl = n * 16 + fr;
        float s = 0.f;
        #pragma unroll
        for (int j = 0; j < 8; ++j) s += ssp[cl * 8 + j];
        rn[n] = rsqrtf(s);
    }

    // C/D layout: col = lane&15, row = (lane>>4)*4 + i
    #pragma unroll
    for (int m = 0; m < 4; ++m) {
        const int r = wid * 64 + m * 16 + ((lane >> 4) << 2);
        #pragma unroll
        for (int n = 0; n < 4; ++n) {
            const int c = colBase + n * 16 + fr;
            if (c < NCLS) {
                #pragma unroll
                for (int i = 0; i < 4; ++i) {
                    float vv = acc[m][n][i] * rn[n];
                    vv = fminf(fmaxf(vv, lo), hi);
                    out[(size_t)(r + i) * NCLS + c] = 64.0f * vv;
                }
            }
        }
    }
}

// Label-column margin fixup (t recovered exactly: /64 is a pow2 scale).
__global__ void arcface_fixup(const int* __restrict__ label, float* __restrict__ out) {
    const int n = blockIdx.x * 64 + threadIdx.x;
    if (n >= NROWS) return;
    const int c = label[n];
    const size_t idx = (size_t)n * NCLS + c;
    const float t = out[idx] * 0.015625f;      // /64
    const float COSM = 0.8775825618903728f;    // cos(0.5)
    const float SINM = 0.479425538604203f;     // sin(0.5)
    const float MM   = 0.2397127693021015f;    // sin(0.5)*0.5
    const float THRESH = -0.8775825618903728f; // cos(pi-0.5)
    float r;
    if (t > THRESH) {
        r = t * COSM - sqrtf(fmaxf(1.0f - t * t, 0.0f)) * SINM;
    } else {
        r = t - MM;
    }
    out[idx] = 64.0f * r;
}

extern "C" void kernel_launch(void* const* d_in, const int* in_sizes, int n_in,
                              void* d_out, int out_size, void* d_ws, size_t ws_size,
                              hipStream_t stream) {
    const float* x     = (const float*)d_in[0];
    const int*   label = (const int*)d_in[1];
    const float* w     = (const float*)d_in[2];
    float* out = (float*)d_out;

    unsigned short* Abf = (unsigned short*)d_ws;   // 512*512 bf16

    rownorm_x<<<NROWS / 4, 256, 0, stream>>>(x, Abf);

    dim3 grid((NCLS + BN - 1) / BN);   // 1563 blocks, one 64-class panel each
    arcface_gemm_fused<<<grid, 512, 0, stream>>>(Abf, w, out);

    arcface_fixup<<<(NROWS + 63) / 64, 64, 0, stream>>>(label, out);
}

// Round 5
// 429.428 us; speedup vs baseline: 1.0443x; 1.0443x over previous
//
#include <hip/hip_runtime.h>
#include <hip/hip_bf16.h>
#include <stdint.h>

// ArcFace: out[n][c] = 64 * margin(clip( x_hat . w_hat_c ))
// N=512, D=512, C=100000.
// R4 (resubmit after broker timeout): two-pass (R1 structure, fastest measured)
// + XCD-grouped GEMM grid so each 128-class W panel is read from HBM ~once,
// + rownorm_x folded into the rownorm_w dispatch.

#define NROWS 512
#define DDIM 512
#define NCLS 100000
#define NCLS_PAD 100096   // 782 * 128

typedef __attribute__((ext_vector_type(8))) short bf16x8;
typedef __attribute__((ext_vector_type(4))) float f32x4;

__device__ __forceinline__ unsigned short f2bf(float x) {
    union { float f; uint32_t u; } c; c.f = x;
    uint32_t r = (c.u + 0x7FFFu + ((c.u >> 16) & 1u)) >> 16;
    return (unsigned short)r;
}

__device__ __forceinline__ void g2lds16(const void* g, void* l) {
    __builtin_amdgcn_global_load_lds(
        (const __attribute__((address_space(1))) void*)g,
        (__attribute__((address_space(3))) void*)l, 16, 0, 0);
}

// One wave per row. Blocks [0,128): x rows -> Abf. Blocks [128, 25152): W rows
// -> Wbf (rows >= NCLS zero-padded). 307 MB traffic, BW-bound.
__global__ __launch_bounds__(256)
void rownorm_all(const float* __restrict__ x, const float* __restrict__ w,
                 unsigned short* __restrict__ Abf, unsigned short* __restrict__ Wbf) {
    const int wv   = threadIdx.x >> 6;
    const int lane = threadIdx.x & 63;

    const float* in;
    unsigned short* orow;
    int validRows, row;
    if (blockIdx.x < 128) {
        row = blockIdx.x * 4 + wv;
        in = x; orow = Abf + (size_t)row * DDIM; validRows = NROWS;
    } else {
        row = (blockIdx.x - 128) * 4 + wv;
        in = w; orow = Wbf + (size_t)row * DDIM; validRows = NCLS;
    }

    if (row >= validRows) {   // zero-pad rows NCLS..NCLS_PAD
        ushort4 z = {0, 0, 0, 0};
        *(ushort4*)(orow + lane * 4) = z;
        *(ushort4*)(orow + 256 + lane * 4) = z;
        return;
    }

    const float4* p = (const float4*)(in + (size_t)row * DDIM);
    float4 v0 = p[lane];
    float4 v1 = p[64 + lane];

    float ss = v0.x*v0.x + v0.y*v0.y + v0.z*v0.z + v0.w*v0.w
             + v1.x*v1.x + v1.y*v1.y + v1.z*v1.z + v1.w*v1.w;
    #pragma unroll
    for (int off = 32; off > 0; off >>= 1) ss += __shfl_xor(ss, off);
    const float r = rsqrtf(ss);

    ushort4 o0, o1;
    o0.x = f2bf(v0.x * r); o0.y = f2bf(v0.y * r);
    o0.z = f2bf(v0.z * r); o0.w = f2bf(v0.w * r);
    o1.x = f2bf(v1.x * r); o1.y = f2bf(v1.y * r);
    o1.z = f2bf(v1.z * r); o1.w = f2bf(v1.w * r);
    *(ushort4*)(orow + lane * 4) = o0;
    *(ushort4*)(orow + 256 + lane * 4) = o1;
}

// 128x128 bf16 MFMA GEMM (m97 structure, unchanged from R1 except grid map).
// Grid: 1D, 3128 blocks = 782 panels x 4 row-tiles. XCD-grouping: the 4 blocks
// of panel P get ids {g*32 + s*8 + (P&7)} -> same bid%8 residue (same XCD,
// assuming round-robin dispatch) within a 32-block window -> W panel fetched
// from HBM once, reused from that XCD's L2.
__global__ __launch_bounds__(256)
void arcface_gemm(const unsigned short* __restrict__ A,
                  const unsigned short* __restrict__ B,
                  float* __restrict__ out) {
    __shared__ unsigned short As[128 * 32];
    __shared__ unsigned short Bs[128 * 32];

    const int bid = blockIdx.x;
    int panel, slot;
    if (bid < 3104) { panel = (bid >> 5) * 8 + (bid & 7); slot = (bid >> 3) & 3; }
    else            { int l = bid - 3104; panel = 776 + l % 6; slot = l / 6; }
    const int rowBase = slot * 128;
    const int colBase = panel * 128;

    const int t    = threadIdx.x;
    const int lane = t & 63;
    const int wid  = t >> 6;
    const int wr   = wid >> 1;
    const int wc   = wid & 1;

    f32x4 acc[4][4] = {};

    const unsigned short* gA = A + (size_t)(rowBase + (t >> 2)) * DDIM + ((t & 3) << 3);
    const unsigned short* gB = B + (size_t)(colBase + (t >> 2)) * DDIM + ((t & 3) << 3);

    const int kg = (lane >> 4) << 3;
    const int fr = lane & 15;

    for (int kt = 0; kt < DDIM; kt += 32) {
        __syncthreads();
        g2lds16(gA + kt,             &As[t * 8]);
        g2lds16(gA + kt + 64 * DDIM, &As[2048 + t * 8]);
        g2lds16(gB + kt,             &Bs[t * 8]);
        g2lds16(gB + kt + 64 * DDIM, &Bs[2048 + t * 8]);
        __syncthreads();

        bf16x8 a[4], b[4];
        #pragma unroll
        for (int m = 0; m < 4; ++m)
            a[m] = *(const bf16x8*)&As[(wr * 64 + m * 16 + fr) * 32 + kg];
        #pragma unroll
        for (int n = 0; n < 4; ++n)
            b[n] = *(const bf16x8*)&Bs[(wc * 64 + n * 16 + fr) * 32 + kg];

        #pragma unroll
        for (int m = 0; m < 4; ++m)
            #pragma unroll
            for (int n = 0; n < 4; ++n)
                acc[m][n] = __builtin_amdgcn_mfma_f32_16x16x32_bf16(
                    a[m], b[n], acc[m][n], 0, 0, 0);
    }

    const float lo = -1.0f + 1e-7f, hi = 1.0f - 1e-7f;
    // C/D layout: col = lane&15, row = (lane>>4)*4 + i
    #pragma unroll
    for (int m = 0; m < 4; ++m) {
        const int r = rowBase + wr * 64 + m * 16 + ((lane >> 4) << 2);
        #pragma unroll
        for (int n = 0; n < 4; ++n) {
            const int c = colBase + wc * 64 + n * 16 + fr;
            if (c < NCLS) {
                #pragma unroll
                for (int i = 0; i < 4; ++i) {
                    float v = acc[m][n][i];
                    v = fminf(fmaxf(v, lo), hi);
                    out[(size_t)(r + i) * NCLS + c] = 64.0f * v;
                }
            }
        }
    }
}

// Label-column margin fixup (t recovered exactly: /64 is a pow2 scale).
__global__ void arcface_fixup(const int* __restrict__ label, float* __restrict__ out) {
    const int n = blockIdx.x * 64 + threadIdx.x;
    if (n >= NROWS) return;
    const int c = label[n];
    const size_t idx = (size_t)n * NCLS + c;
    const float t = out[idx] * 0.015625f;      // /64
    const float COSM = 0.8775825618903728f;    // cos(0.5)
    const float SINM = 0.479425538604203f;     // sin(0.5)
    const float MM   = 0.2397127693021015f;    // sin(0.5)*0.5
    const float THRESH = -0.8775825618903728f; // cos(pi-0.5)
    float r;
    if (t > THRESH) {
        r = t * COSM - sqrtf(fmaxf(1.0f - t * t, 0.0f)) * SINM;
    } else {
        r = t - MM;
    }
    out[idx] = 64.0f * r;
}

extern "C" void kernel_launch(void* const* d_in, const int* in_sizes, int n_in,
                              void* d_out, int out_size, void* d_ws, size_t ws_size,
                              hipStream_t stream) {
    const float* x     = (const float*)d_in[0];
    const int*   label = (const int*)d_in[1];
    const float* w     = (const float*)d_in[2];
    float* out = (float*)d_out;

    unsigned short* Abf = (unsigned short*)d_ws;                        // 512*512
    unsigned short* Wbf = (unsigned short*)d_ws + (size_t)NROWS * DDIM; // 100096*512

    // 128 x-blocks + 25024 w-blocks, 4 rows each
    rownorm_all<<<128 + NCLS_PAD / 4, 256, 0, stream>>>(x, w, Abf, Wbf);

    arcface_gemm<<<3128, 256, 0, stream>>>(Abf, Wbf, out);

    arcface_fixup<<<(NROWS + 63) / 64, 64, 0, stream>>>(label, out);
}